// Round 7
// baseline (288.726 us; speedup 1.0000x reference)
//
#include <hip/hip_runtime.h>
#include <hip/hip_fp16.h>

#define N_NODES 100000
#define N_EDGES 1600000
#define HDIM    128
#define NGRAPH  256
#define NRES    8          // XCD count; residue classes for write-locality
#define PAD     64         // adjacency slots per node (Poisson(16): P(>64)~e^-128)

typedef __attribute__((ext_vector_type(8))) short short8;
typedef __attribute__((ext_vector_type(8))) _Float16 half8;
typedef __attribute__((ext_vector_type(4))) float f32x4;

__device__ inline uint pkadd(uint a, uint b) {
    __half2 r = __hadd2(__builtin_bit_cast(__half2, a), __builtin_bit_cast(__half2, b));
    return __builtin_bit_cast(uint, r);
}
__device__ inline uint4 pkadd4(uint4 a, uint4 b) {
    a.x = pkadd(a.x, b.x); a.y = pkadd(a.y, b.y);
    a.z = pkadd(a.z, b.z); a.w = pkadd(a.w, b.w);
    return a;
}
__device__ inline ushort f2h(float x) { return __half_as_ushort(__float2half_rn(x)); }
__device__ inline float h2f(ushort h) { return __half2float(__ushort_as_half(h)); }

// ============ padded-adjacency build (residue-partitioned) =================
__global__ __launch_bounds__(256) void scatter_pad_kernel(
        const int* __restrict__ src, const int* __restrict__ dst,
        int* __restrict__ cnt, int* __restrict__ eadj, int E) {
    int res  = blockIdx.x & (NRES - 1);
    int grp  = blockIdx.x >> 3;
    int ngrp = gridDim.x >> 3;
    int lo = res * (N_NODES / NRES), hi = lo + (N_NODES / NRES);
    for (int e = grp * 256 + threadIdx.x; e < E; e += ngrp * 256) {
        int d = dst[e];
        if (d >= lo && d < hi) {
            int p = atomicAdd(&cnt[d], 1);
            if (p < PAD) eadj[d * PAD + p] = src[e];
        }
    }
}

// ============ fp32 -> fp16 convert (layer-0 input) =========================
__global__ __launch_bounds__(256) void f2h_kernel(const float* __restrict__ x,
                                                  ushort* __restrict__ xh, int n4) {
    for (int i = blockIdx.x * 256 + threadIdx.x; i < n4; i += gridDim.x * 256) {
        float4 v = ((const float4*)x)[i];
        ushort4 o;
        o.x = f2h(v.x); o.y = f2h(v.y); o.z = f2h(v.z); o.w = f2h(v.w);
        ((ushort4*)xh)[i] = o;
    }
}

// ============ weight pre-pack: fp32 -> split fp16, frag-major ==============
// packed idx(ks, cfg, lane, i) = (((ks*8 + cfg)*64 + lane)*8 + i)
// element: W[k][c], k = ks*32 + (lane>>4)*8 + i, c = cfg*16 + (lane&15)
__global__ void pack4_kernel(const float* __restrict__ wa, const float* __restrict__ wb,
                             const float* __restrict__ wc, const float* __restrict__ wd,
                             ushort* __restrict__ ha, ushort* __restrict__ la,
                             ushort* __restrict__ hb, ushort* __restrict__ lb,
                             ushort* __restrict__ hc, ushort* __restrict__ lc,
                             ushort* __restrict__ hd, ushort* __restrict__ ld) {
    int sel = blockIdx.x >> 6;
    const float* w = sel == 0 ? wa : sel == 1 ? wb : sel == 2 ? wc : wd;
    ushort* hi = sel == 0 ? ha : sel == 1 ? hb : sel == 2 ? hc : hd;
    ushort* lo = sel == 0 ? la : sel == 1 ? lb : sel == 2 ? lc : ld;
    int t = (blockIdx.x & 63) * 256 + threadIdx.x;
    int i = t & 7, lane = (t >> 3) & 63, cfg = (t >> 9) & 7, ks = t >> 12;
    int k = ks * 32 + (lane >> 4) * 8 + i;
    int c = cfg * 16 + (lane & 15);
    float v = w[k * 128 + c];
    ushort h = f2h(v);
    hi[t] = h;
    lo[t] = f2h(v - h2f(h));
}

// ============ fused GIN layer: fp16 gather-agg -> split-fp16 MFMA MLP ======
// BM=32 rows/block (grid*32 == N exactly), 4 waves; wave wv owns rows
// wv*8..wv*8+7 for gather and output cols [wv*32,wv*32+32) for MFMA.
// Gather: deep-prefetch cnt+adjacency for all 8 rows (kills serial
// round-trips), then paired-row loop: 16 lanes per source row (16B/lane),
// 4 sources/row/step x 2 rows in flight; packed half2 accumulation.
// MFMA: A = z (exact fp16), W split hi+lo fp16 -> 2 MFMAs per product.
// Output H staged in LDS -> coalesced 16B/lane global writes.
// LAST: + fused fp32 gate scores.
template<bool LAST>
__global__ __launch_bounds__(256, 8) void gin_layer_kernel(
        const ushort* __restrict__ hin,
        const int* __restrict__ cnt, const int* __restrict__ eadj,
        const ushort* __restrict__ w1h, const ushort* __restrict__ w1l,
        const float* __restrict__ b1,
        const ushort* __restrict__ w2h, const ushort* __restrict__ w2l,
        const float* __restrict__ b2,
        ushort* __restrict__ hout,
        const float* __restrict__ gw, const float* __restrict__ gb,
        float* __restrict__ gateb) {
    __shared__ ushort zt[32 * 128];   // z tile, fp16, swizzled (reused: H stage)
    __shared__ ushort tt[32 * 128];   // T tile, fp16, swizzled (reused: gate scratch)
    int tid  = threadIdx.x;
    int lane = tid & 63;
    int wv   = tid >> 6;
    int wvs  = __builtin_amdgcn_readfirstlane(wv);
    int row0 = blockIdx.x * 32;
    int cfg0 = wvs * 2;
    int g    = lane >> 4;        // source-slot group / k-group
    int q    = lane & 15;        // 16B column chunk / frag row / frag col
    const uint4* h4 = (const uint4*)hin;   // 16 uint4 per 256B row

    // ---- prefetch: degree + full adjacency row for all 8 owned rows ----
    int baseRow = row0 + wvs * 8;
    int al[8], dg[8];
    #pragma unroll
    for (int j = 0; j < 8; j++) {
        al[j] = eadj[(baseRow + j) * PAD + lane];
        int d = cnt[baseRow + j];
        dg[j] = d > PAD ? PAD : d;
    }

    // ---- gather: 4 row-pairs, 2x4 sources in flight per step ----
    #pragma unroll
    for (int jp = 0; jp < 4; jp++) {
        int lrA = wvs * 8 + 2 * jp, lrB = lrA + 1;
        int rowA = row0 + lrA, rowB = rowA + 1;
        int dA = dg[2 * jp], dB = dg[2 * jp + 1];
        uint4 accA = make_uint4(0u, 0u, 0u, 0u);
        uint4 accB = make_uint4(0u, 0u, 0u, 0u);
        int dmax = dA > dB ? dA : dB;
        int nch = (dmax + 4) >> 2;          // ceil((deg+1)/4), self folded as jj=-1
        for (int c = 0; c < nch; c++) {
            int jj = 4 * c + g - 1;
            int s = jj < 0 ? 0 : jj;
            int nbA = __shfl(al[2 * jp], s);
            int nbB = __shfl(al[2 * jp + 1], s);
            int idxA = jj < 0 ? rowA : nbA;
            int idxB = jj < 0 ? rowB : nbB;
            if (jj < dA) accA = pkadd4(accA, h4[idxA * 16 + q]);
            if (jj < dB) accB = pkadd4(accB, h4[idxB * 16 + q]);
        }
        #pragma unroll
        for (int off = 16; off <= 32; off <<= 1) {
            accA.x = pkadd(accA.x, (uint)__shfl_xor((int)accA.x, off));
            accA.y = pkadd(accA.y, (uint)__shfl_xor((int)accA.y, off));
            accA.z = pkadd(accA.z, (uint)__shfl_xor((int)accA.z, off));
            accA.w = pkadd(accA.w, (uint)__shfl_xor((int)accA.w, off));
            accB.x = pkadd(accB.x, (uint)__shfl_xor((int)accB.x, off));
            accB.y = pkadd(accB.y, (uint)__shfl_xor((int)accB.y, off));
            accB.z = pkadd(accB.z, (uint)__shfl_xor((int)accB.z, off));
            accB.w = pkadd(accB.w, (uint)__shfl_xor((int)accB.w, off));
        }
        if (g == 0) {
            *(uint4*)((char*)zt + ((lrA * 256 + q * 16) ^ ((lrA & 7) << 4))) = accA;
            *(uint4*)((char*)zt + ((lrB * 256 + q * 16) ^ ((lrB & 7) << 4))) = accB;
        }
    }
    __syncthreads();

    f32x4 acc[2][2];
    // ================= phase 1: T = relu(Z@W1 + b1) -> tt ==================
    #pragma unroll
    for (int rf = 0; rf < 2; rf++)
        #pragma unroll
        for (int cf = 0; cf < 2; cf++) acc[rf][cf] = (f32x4){0.f, 0.f, 0.f, 0.f};

    for (int ks = 0; ks < 4; ks++) {
        half8 bh[2], bl[2];
        #pragma unroll
        for (int cf = 0; cf < 2; cf++) {
            int bidx = (((ks * 8 + cfg0 + cf) * 64 + lane) * 8);
            bh[cf] = __builtin_bit_cast(half8, *(const short8*)&w1h[bidx]);
            bl[cf] = __builtin_bit_cast(half8, *(const short8*)&w1l[bidx]);
        }
        #pragma unroll
        for (int rf = 0; rf < 2; rf++) {
            int r = rf * 16 + q;
            int off = (r * 256 + ks * 64 + g * 16) ^ ((r & 7) << 4);
            half8 a = __builtin_bit_cast(half8, *(const short8*)((const char*)zt + off));
            #pragma unroll
            for (int cf = 0; cf < 2; cf++) {
                acc[rf][cf] = __builtin_amdgcn_mfma_f32_16x16x32_f16(a, bh[cf], acc[rf][cf], 0, 0, 0);
                acc[rf][cf] = __builtin_amdgcn_mfma_f32_16x16x32_f16(a, bl[cf], acc[rf][cf], 0, 0, 0);
            }
        }
    }

    // epilogue 1: bias + relu -> fp16 tt (swizzled)
    #pragma unroll
    for (int cf = 0; cf < 2; cf++) {
        int c = (cfg0 + cf) * 16 + q;
        float bias = b1[c];
        #pragma unroll
        for (int rf = 0; rf < 2; rf++) {
            #pragma unroll
            for (int i = 0; i < 4; i++) {
                int r = rf * 16 + g * 4 + i;
                float v = fmaxf(acc[rf][cf][i] + bias, 0.f);
                int off = (r * 256 + c * 2) ^ ((r & 7) << 4);
                *(ushort*)((char*)tt + off) = f2h(v);
            }
        }
    }
    __syncthreads();

    // ================= phase 2: H = relu(T@W2 + b2) ========================
    #pragma unroll
    for (int rf = 0; rf < 2; rf++)
        #pragma unroll
        for (int cf = 0; cf < 2; cf++) acc[rf][cf] = (f32x4){0.f, 0.f, 0.f, 0.f};

    for (int ks = 0; ks < 4; ks++) {
        half8 bh[2], bl[2];
        #pragma unroll
        for (int cf = 0; cf < 2; cf++) {
            int bidx = (((ks * 8 + cfg0 + cf) * 64 + lane) * 8);
            bh[cf] = __builtin_bit_cast(half8, *(const short8*)&w2h[bidx]);
            bl[cf] = __builtin_bit_cast(half8, *(const short8*)&w2l[bidx]);
        }
        #pragma unroll
        for (int rf = 0; rf < 2; rf++) {
            int r = rf * 16 + q;
            int off = (r * 256 + ks * 64 + g * 16) ^ ((r & 7) << 4);
            half8 a = __builtin_bit_cast(half8, *(const short8*)((const char*)tt + off));
            #pragma unroll
            for (int cf = 0; cf < 2; cf++) {
                acc[rf][cf] = __builtin_amdgcn_mfma_f32_16x16x32_f16(a, bh[cf], acc[rf][cf], 0, 0, 0);
                acc[rf][cf] = __builtin_amdgcn_mfma_f32_16x16x32_f16(a, bl[cf], acc[rf][cf], 0, 0, 0);
            }
        }
    }

    // epilogue 2: bias + relu -> stage fp16 into zt (+ gate partials if LAST)
    float pg[8];
    if (LAST) {
        #pragma unroll
        for (int p = 0; p < 8; p++) pg[p] = 0.f;
    }
    #pragma unroll
    for (int cf = 0; cf < 2; cf++) {
        int c = (cfg0 + cf) * 16 + q;
        float bias = b2[c];
        float gwc = LAST ? gw[c] : 0.f;
        #pragma unroll
        for (int rf = 0; rf < 2; rf++) {
            #pragma unroll
            for (int i = 0; i < 4; i++) {
                int r = rf * 16 + g * 4 + i;
                float v = fmaxf(acc[rf][cf][i] + bias, 0.f);
                int off = (r * 256 + c * 2) ^ ((r & 7) << 4);
                *(ushort*)((char*)zt + off) = f2h(v);
                if (LAST) pg[rf * 4 + i] += v * gwc;
            }
        }
    }
    __syncthreads();

    // coalesced H write: 16B/lane, 1KB contiguous per wave-instruction
    #pragma unroll
    for (int p = 0; p < 2; p++) {
        int idx = tid + 256 * p;            // 0..511 = 32 rows x 16 chunks
        int r = idx >> 4, ch = idx & 15;
        uint4 v = *(const uint4*)((const char*)zt + ((r * 256 + ch * 16) ^ ((r & 7) << 4)));
        ((uint4*)hout)[(size_t)(row0 + r) * 16 + ch] = v;
    }

    if (LAST) {
        #pragma unroll
        for (int off = 1; off < 16; off <<= 1)
            #pragma unroll
            for (int p = 0; p < 8; p++) pg[p] += __shfl_xor(pg[p], off);
        float* gpart = (float*)tt;     // [4 waves][32 rows] (tt free after phase 2)
        if (q == 0) {
            #pragma unroll
            for (int rf = 0; rf < 2; rf++)
                #pragma unroll
                for (int i = 0; i < 4; i++)
                    gpart[wvs * 32 + rf * 16 + g * 4 + i] = pg[rf * 4 + i];
        }
        __syncthreads();
        if (tid < 32) {
            gateb[row0 + tid] = gpart[tid] + gpart[32 + tid] + gpart[64 + tid]
                              + gpart[96 + tid] + gb[0];
        }
    }
}

// ======================== attention readout + both heads ===================
__device__ inline int lower_bound_i(const int* a, int n, int v) {
    int lo = 0, hi = n;
    while (lo < hi) {
        int mid = (lo + hi) >> 1;
        if (a[mid] < v) lo = mid + 1; else hi = mid;
    }
    return lo;
}

// 512 threads = 8 waves; weighted feature sum is wave-per-row (8 rows in flight)
__global__ __launch_bounds__(512) void readout_kernel(
        const ushort* __restrict__ h2h, const float* __restrict__ gate,
        const int* __restrict__ batch,
        const float* __restrict__ cw1, const float* __restrict__ cb1,
        const float* __restrict__ cw2, const float* __restrict__ cb2,
        const float* __restrict__ rw1, const float* __restrict__ rb1,
        const float* __restrict__ rw2, const float* __restrict__ rb2,
        float* __restrict__ out) {
    int g = blockIdx.x, t = threadIdx.x;
    int wv = t >> 6, lane = t & 63;
    __shared__ int   bounds[2];
    __shared__ float red[512];
    __shared__ float part[8][128];
    __shared__ float gv[128];
    __shared__ float t1c[128], t1r[128];
    if (t == 0) {
        bounds[0] = lower_bound_i(batch, N_NODES, g);
        bounds[1] = lower_bound_i(batch, N_NODES, g + 1);
    }
    __syncthreads();
    int s = bounds[0], e = bounds[1];

    float m = -3.4e38f;
    for (int i = s + t; i < e; i += 512) m = fmaxf(m, gate[i]);
    red[t] = m;
    __syncthreads();
    for (int off = 256; off; off >>= 1) {
        if (t < off) red[t] = fmaxf(red[t], red[t + off]);
        __syncthreads();
    }
    m = red[0];
    __syncthreads();

    float dsum = 0.f;
    for (int i = s + t; i < e; i += 512) dsum += expf(gate[i] - m);
    red[t] = dsum;
    __syncthreads();
    for (int off = 256; off; off >>= 1) {
        if (t < off) red[t] += red[t + off];
        __syncthreads();
    }
    float denom = red[0];
    float invd = (e > s && denom > 0.f) ? 1.f / denom : 0.f;

    // weighted feature sum: wave wv handles rows s+wv, s+wv+8, ...
    const uint* h2u = (const uint*)h2h;
    float a0 = 0.f, a1 = 0.f, b0 = 0.f, b1v = 0.f;
    int i0 = s + wv;
    for (; i0 + 8 < e; i0 += 16) {
        float w0 = expf(gate[i0] - m);
        float w1 = expf(gate[i0 + 8] - m);
        __half2 v0 = __builtin_bit_cast(__half2, h2u[(size_t)i0 * 64 + lane]);
        __half2 v1 = __builtin_bit_cast(__half2, h2u[(size_t)(i0 + 8) * 64 + lane]);
        a0 += w0 * __low2float(v0); a1 += w0 * __high2float(v0);
        b0 += w1 * __low2float(v1); b1v += w1 * __high2float(v1);
    }
    if (i0 < e) {
        float w0 = expf(gate[i0] - m);
        __half2 v0 = __builtin_bit_cast(__half2, h2u[(size_t)i0 * 64 + lane]);
        a0 += w0 * __low2float(v0); a1 += w0 * __high2float(v0);
    }
    part[wv][lane * 2]     = a0 + b0;
    part[wv][lane * 2 + 1] = a1 + b1v;
    __syncthreads();
    if (t < 128) {
        float acc = 0.f;
        #pragma unroll
        for (int w = 0; w < 8; w++) acc += part[w][t];
        gv[t] = acc * invd;
    }
    __syncthreads();

    if (t < 128) {
        float a = cb1[t];
        for (int k = 0; k < HDIM; k++) a += gv[k] * cw1[k * HDIM + t];
        t1c[t] = fmaxf(a, 0.f);
    } else if (t < 256) {
        int tf = t - 128;
        float a = rb1[tf];
        for (int k = 0; k < HDIM; k++) a += gv[k] * rw1[k * HDIM + tf];
        t1r[tf] = fmaxf(a, 0.f);
    }
    __syncthreads();

    if (t < 9) {
        float acc2 = cb2[t];
        for (int k = 0; k < HDIM; k++) acc2 += t1c[k] * cw2[k * 9 + t];
        out[g * 9 + t] = acc2;
    }
    if (t == 64) {
        float acc2 = rb2[0];
        for (int k = 0; k < HDIM; k++) acc2 += t1r[k] * rw2[k];
        out[NGRAPH * 9 + g] = acc2;
    }
}

// ======================== launch ===========================================
extern "C" void kernel_launch(void* const* d_in, const int* in_sizes, int n_in,
                              void* d_out, int out_size, void* d_ws, size_t ws_size,
                              hipStream_t stream) {
    const float* x     = (const float*)d_in[0];
    const int*   ei    = (const int*)d_in[1];
    const int*   batch = (const int*)d_in[2];
    const float *l0w1 = (const float*)d_in[3],  *l0b1 = (const float*)d_in[4];
    const float *l0w2 = (const float*)d_in[5],  *l0b2 = (const float*)d_in[6];
    const float *l1w1 = (const float*)d_in[7],  *l1b1 = (const float*)d_in[8];
    const float *l1w2 = (const float*)d_in[9],  *l1b2 = (const float*)d_in[10];
    const float *gw   = (const float*)d_in[11], *gb   = (const float*)d_in[12];
    const float *cw1  = (const float*)d_in[13], *cb1  = (const float*)d_in[14];
    const float *cw2  = (const float*)d_in[15], *cb2  = (const float*)d_in[16];
    const float *rw1  = (const float*)d_in[17], *rb1  = (const float*)d_in[18];
    const float *rw2  = (const float*)d_in[19], *rb2  = (const float*)d_in[20];
    const int* src = ei;
    const int* dst = ei + N_EDGES;
    float* out = (float*)d_out;

    char* ws = (char*)d_ws;
    size_t o = 0;
    auto alloc = [&](size_t bytes) { void* p = ws + o; o = (o + bytes + 255) & ~(size_t)255; return p; };
    ushort* h2h   = (ushort*)alloc((size_t)N_NODES * HDIM * 2);  // fp16 layer-2 out
    ushort* xh    = h2h;                                          // fp16 x aliases h2h (dead before h2h written)
    ushort* h1h   = (ushort*)alloc((size_t)N_NODES * HDIM * 2);  // fp16 layer-1 out
    int*    eadj  = (int*)alloc((size_t)N_NODES * PAD * 4);
    int*    cnt   = (int*)alloc(N_NODES * 4);
    float*  gateb = (float*)alloc(N_NODES * 4);
    ushort* w0h1 = (ushort*)alloc(16384 * 2), *w0l1 = (ushort*)alloc(16384 * 2);
    ushort* w0h2 = (ushort*)alloc(16384 * 2), *w0l2 = (ushort*)alloc(16384 * 2);
    ushort* w1h1 = (ushort*)alloc(16384 * 2), *w1l1 = (ushort*)alloc(16384 * 2);
    ushort* w1h2 = (ushort*)alloc(16384 * 2), *w1l2 = (ushort*)alloc(16384 * 2);
    (void)ws_size; (void)in_sizes; (void)n_in; (void)out_size;

    pack4_kernel<<<256, 256, 0, stream>>>(l0w1, l0w2, l1w1, l1w2,
                                          w0h1, w0l1, w0h2, w0l2,
                                          w1h1, w1l1, w1h2, w1l2);

    hipMemsetAsync(cnt, 0, N_NODES * 4, stream);
    scatter_pad_kernel<<<2048, 256, 0, stream>>>(src, dst, cnt, eadj, N_EDGES);
    f2h_kernel<<<1024, 256, 0, stream>>>(x, xh, N_NODES * HDIM / 4);

    const int layerBlocks = N_NODES / 32;   // 3125, exact (N % 32 == 0)
    gin_layer_kernel<false><<<layerBlocks, 256, 0, stream>>>(
        xh, cnt, eadj, w0h1, w0l1, l0b1, w0h2, w0l2, l0b2,
        h1h, gw, gb, nullptr);
    gin_layer_kernel<true><<<layerBlocks, 256, 0, stream>>>(
        h1h, cnt, eadj, w1h1, w1l1, l1b1, w1h2, w1l2, l1b2,
        h2h, gw, gb, gateb);

    readout_kernel<<<NGRAPH, 512, 0, stream>>>(h2h, gateb, batch,
                                               cw1, cb1, cw2, cb2,
                                               rw1, rb1, rw2, rb2, out);
}